// Round 1
// baseline (457.801 us; speedup 1.0000x reference)
//
#include <hip/hip_runtime.h>

// ---------------------------------------------------------------------------
// MoE block: x[2,2048,1024] fp32, 8 experts, top-2 routing, f=2048, LN output.
// Strategy: fp32 gating (exact top-k) -> expert bucketing -> bf16 MFMA grouped
// GEMMs (only top-2 experts computed) -> fused residual+LayerNorm.
// ---------------------------------------------------------------------------

typedef unsigned short ushort_t;
typedef short short8 __attribute__((ext_vector_type(8)));
typedef float f32x4 __attribute__((ext_vector_type(4)));

#define T_TOKENS 4096
#define DMODEL 1024
#define FFN 2048
#define NEXP 8
#define MAXSLOTS 9216   // 8192 assignments + 8*128 padding headroom

__device__ __forceinline__ ushort_t f2bf(float f) {
    unsigned u = __float_as_uint(f);
    unsigned r = (u + 0x7fffu + ((u >> 16) & 1u)) >> 16;
    return (ushort_t)r;
}

__device__ __forceinline__ void gload_lds16(const void* g, void* l) {
    __builtin_amdgcn_global_load_lds(
        (const __attribute__((address_space(1))) unsigned int*)g,
        (__attribute__((address_space(3))) unsigned int*)l,
        16, 0, 0);
}

// ---------------------------------------------------------------------------
// 1) init: counts/cursor = 0, slot_token = -1
__global__ void init_kernel(int* counts, int* cursor, int* slot_token) {
    int i = blockIdx.x * 256 + threadIdx.x;
    if (i < NEXP) { counts[i] = 0; cursor[i] = 0; }
    if (i < MAXSLOTS) slot_token[i] = -1;
}

// ---------------------------------------------------------------------------
// 2) gating: fp32 logits, top-2, softmax weights; atomic expert counts.
//    One wave per token.
__global__ __launch_bounds__(64) void gate_kernel(
    const float* __restrict__ x, const float* __restrict__ Wg,
    const float* __restrict__ bg,
    int* __restrict__ top_idx, float* __restrict__ top_w,
    int* __restrict__ counts)
{
    int t = blockIdx.x;
    int lane = threadIdx.x;
    const float* xr = x + (size_t)t * DMODEL;
    float acc[8] = {0.f,0.f,0.f,0.f,0.f,0.f,0.f,0.f};
    #pragma unroll
    for (int i = 0; i < DMODEL / 64; i++) {
        int d = lane + i * 64;
        float xv = xr[d];
        const float4* wr = (const float4*)&Wg[d * 8];
        float4 wa = wr[0], wb = wr[1];
        acc[0] += xv * wa.x; acc[1] += xv * wa.y;
        acc[2] += xv * wa.z; acc[3] += xv * wa.w;
        acc[4] += xv * wb.x; acc[5] += xv * wb.y;
        acc[6] += xv * wb.z; acc[7] += xv * wb.w;
    }
    #pragma unroll
    for (int off = 32; off > 0; off >>= 1) {
        #pragma unroll
        for (int e = 0; e < 8; e++) acc[e] += __shfl_down(acc[e], off);
    }
    if (lane == 0) {
        float l[8];
        #pragma unroll
        for (int e = 0; e < 8; e++) l[e] = acc[e] + bg[e];
        int i0 = 0; float v0 = l[0];
        #pragma unroll
        for (int e = 1; e < 8; e++) if (l[e] > v0) { v0 = l[e]; i0 = e; }
        int i1 = -1; float v1 = -1e30f;
        #pragma unroll
        for (int e = 0; e < 8; e++) if (e != i0 && l[e] > v1) { v1 = l[e]; i1 = e; }
        float eg = expf(v1 - v0);           // <= 1
        float den = 1.f + eg;
        top_idx[2 * t] = i0; top_idx[2 * t + 1] = i1;
        top_w[2 * t] = 1.f / den; top_w[2 * t + 1] = eg / den;
        atomicAdd(&counts[i0], 1);
        atomicAdd(&counts[i1], 1);
    }
}

// ---------------------------------------------------------------------------
// 3) padded prefix offsets (pad each expert to 128-row tiles)
__global__ void offsets_kernel(const int* counts, int* offs) {
    if (threadIdx.x == 0 && blockIdx.x == 0) {
        int cum = 0;
        for (int e = 0; e < NEXP; e++) {
            offs[e] = cum;
            cum += (counts[e] + 127) & ~127;
        }
        offs[NEXP] = cum;
    }
}

// ---------------------------------------------------------------------------
// 4) scatter: assign each (token, k) a slot in its expert's bucket
__global__ void scatter_kernel(const int* __restrict__ top_idx,
                               const int* __restrict__ offs,
                               int* cursor, int* slot_token, int* slot_of)
{
    int t = blockIdx.x * 256 + threadIdx.x;
    if (t >= T_TOKENS) return;
    #pragma unroll
    for (int k = 0; k < 2; k++) {
        int e = top_idx[2 * t + k];
        int pos = atomicAdd(&cursor[e], 1);
        int slot = offs[e] + pos;
        slot_token[slot] = t;
        slot_of[2 * t + k] = slot;
    }
}

// ---------------------------------------------------------------------------
// 5) gather x rows into bf16 A-matrix (zeros for pad slots)
__global__ __launch_bounds__(256) void gather_kernel(
    const float* __restrict__ x, const int* __restrict__ slot_token,
    ushort_t* __restrict__ Xg)
{
    int srow = blockIdx.x;
    int tok = slot_token[srow];
    ushort_t* dst = Xg + (size_t)srow * DMODEL;
    if (tok < 0) {
        #pragma unroll
        for (int i = 0; i < 4; i++) dst[threadIdx.x + i * 256] = 0;
    } else {
        const float* sx = x + (size_t)tok * DMODEL;
        #pragma unroll
        for (int i = 0; i < 4; i++) {
            int c = threadIdx.x + i * 256;
            dst[c] = f2bf(sx[c]);
        }
    }
}

// ---------------------------------------------------------------------------
// 6) transpose+convert weights: src [E][R][C] f32 -> dst [E][C][R] bf16
__global__ __launch_bounds__(256) void transpose_kernel(
    const float* __restrict__ src, ushort_t* __restrict__ dst, int R, int C)
{
    __shared__ ushort_t tile[64][68];
    const float* s = src + (size_t)blockIdx.z * R * C;
    ushort_t* d = dst + (size_t)blockIdx.z * R * C;
    int c0 = blockIdx.x * 64, r0 = blockIdx.y * 64;
    int tc = threadIdx.x & 63;
    int t4 = threadIdx.x >> 6;
    #pragma unroll
    for (int i = 0; i < 16; i++) {
        int rr = t4 + i * 4;
        tile[rr][tc] = f2bf(s[(size_t)(r0 + rr) * C + c0 + tc]);
    }
    __syncthreads();
    int tr = threadIdx.x & 63;
    #pragma unroll
    for (int i = 0; i < 16; i++) {
        int cc = t4 + i * 4;
        d[(size_t)(c0 + cc) * R + r0 + tr] = tile[tr][cc];
    }
}

// ---------------------------------------------------------------------------
// 7) grouped expert GEMM (m97 structure): C = A[M,K] * Bt[N,K]^T + bias
//    128x128 tile, BK=32, 4 waves, 4x4 mfma_f32_16x16x32_bf16 per wave.
template <int K, int N, bool RELU, typename OutT>
__global__ __launch_bounds__(256) void expert_gemm(
    const ushort_t* __restrict__ A,    // [totalSlots][K] bf16
    const ushort_t* __restrict__ Bt,   // [E][N][K] bf16
    const float* __restrict__ bias,    // [E][N]
    OutT* __restrict__ Cout,           // [totalSlots][N]
    const int* __restrict__ offs)      // [E+1]
{
    const int e  = blockIdx.z;
    const int mt = blockIdx.y;
    const int nt = blockIdx.x;
    const int off_e = offs[e];
    const int Mpad  = offs[e + 1] - off_e;
    if (mt * 128 >= Mpad) return;

    __shared__ __align__(16) ushort_t As[128 * 32];
    __shared__ __align__(16) ushort_t Bs[128 * 32];

    const int tid  = threadIdx.x;
    const int lane = tid & 63;
    const int w    = tid >> 6;
    const int quad = lane >> 4;
    const int r16  = lane & 15;
    const int lrow = lane >> 2;        // 0..15 row within 16-row staging block
    const int lk   = (lane & 3) * 8;   // k element offset for staging

    const size_t arow0 = (size_t)(off_e + mt * 128);
    const ushort_t* aS0 = A + (arow0 + (size_t)(2 * w + 0) * 16 + lrow) * K + lk;
    const ushort_t* aS1 = A + (arow0 + (size_t)(2 * w + 1) * 16 + lrow) * K + lk;
    const ushort_t* Bte = Bt + (size_t)e * N * K;
    const ushort_t* bS0 = Bte + ((size_t)(nt * 128 + (2 * w + 0) * 16 + lrow)) * K + lk;
    const ushort_t* bS1 = Bte + ((size_t)(nt * 128 + (2 * w + 1) * 16 + lrow)) * K + lk;
    ushort_t* aD0 = &As[(2 * w + 0) * 512];
    ushort_t* aD1 = &As[(2 * w + 1) * 512];
    ushort_t* bD0 = &Bs[(2 * w + 0) * 512];
    ushort_t* bD1 = &Bs[(2 * w + 1) * 512];

    const int wm = (w >> 1) * 64;
    const int wn = (w & 1) * 64;

    f32x4 acc[4][4];
    #pragma unroll
    for (int i = 0; i < 4; i++)
        #pragma unroll
        for (int j = 0; j < 4; j++)
            acc[i][j] = (f32x4){0.f, 0.f, 0.f, 0.f};

    for (int k0 = 0; k0 < K; k0 += 32) {
        gload_lds16(aS0 + k0, aD0);
        gload_lds16(aS1 + k0, aD1);
        gload_lds16(bS0 + k0, bD0);
        gload_lds16(bS1 + k0, bD1);
        __syncthreads();
        short8 af[4], bfr[4];
        #pragma unroll
        for (int i = 0; i < 4; i++)
            af[i] = *(const short8*)&As[(wm + i * 16 + r16) * 32 + quad * 8];
        #pragma unroll
        for (int j = 0; j < 4; j++)
            bfr[j] = *(const short8*)&Bs[(wn + j * 16 + r16) * 32 + quad * 8];
        #pragma unroll
        for (int i = 0; i < 4; i++)
            #pragma unroll
            for (int j = 0; j < 4; j++)
                acc[i][j] = __builtin_amdgcn_mfma_f32_16x16x32_bf16(
                    af[i], bfr[j], acc[i][j], 0, 0, 0);
        __syncthreads();
    }

    // epilogue: bias (+relu), write C rows (C/D layout: col=lane&15, row=quad*4+reg)
    const float* be = bias + (size_t)e * N;
    #pragma unroll
    for (int i = 0; i < 4; i++) {
        #pragma unroll
        for (int j = 0; j < 4; j++) {
            int n = nt * 128 + wn + j * 16 + r16;
            float bv = be[n];
            #pragma unroll
            for (int r = 0; r < 4; r++) {
                int m = mt * 128 + wm + i * 16 + quad * 4 + r;
                float v = acc[i][j][r] + bv;
                if (RELU) v = v > 0.f ? v : 0.f;
                size_t idx = (size_t)(off_e + m) * N + n;
                if constexpr (sizeof(OutT) == 2)
                    ((ushort_t*)Cout)[idx] = f2bf(v);
                else
                    ((float*)Cout)[idx] = v;
            }
        }
    }
}

// ---------------------------------------------------------------------------
// 8) fused mix + residual + LayerNorm
__global__ __launch_bounds__(256) void ln_kernel(
    const float* __restrict__ x, const float* __restrict__ O,
    const int* __restrict__ slot_of, const float* __restrict__ top_w,
    const float* __restrict__ gamma, const float* __restrict__ beta,
    float* __restrict__ out)
{
    int t = blockIdx.x;
    int s0 = slot_of[2 * t], s1 = slot_of[2 * t + 1];
    float w0 = top_w[2 * t], w1 = top_w[2 * t + 1];
    const float* xr = x + (size_t)t * DMODEL;
    const float* o0 = O + (size_t)s0 * DMODEL;
    const float* o1 = O + (size_t)s1 * DMODEL;

    float y[4];
    float s = 0.f, sq = 0.f;
    #pragma unroll
    for (int i = 0; i < 4; i++) {
        int c = threadIdx.x + i * 256;
        float v = xr[c] + w0 * o0[c] + w1 * o1[c];
        y[i] = v; s += v; sq += v * v;
    }
    __shared__ float red[2][4];
    #pragma unroll
    for (int off = 32; off > 0; off >>= 1) {
        s += __shfl_down(s, off);
        sq += __shfl_down(sq, off);
    }
    int lane = threadIdx.x & 63, wv = threadIdx.x >> 6;
    if (lane == 0) { red[0][wv] = s; red[1][wv] = sq; }
    __syncthreads();
    if (threadIdx.x == 0) {
        float S = red[0][0] + red[0][1] + red[0][2] + red[0][3];
        float SQ = red[1][0] + red[1][1] + red[1][2] + red[1][3];
        float mu = S * (1.f / DMODEL);
        float var = SQ * (1.f / DMODEL) - mu * mu;
        red[0][0] = mu;
        red[1][0] = rsqrtf(var + 1e-5f);
    }
    __syncthreads();
    float mu = red[0][0], inv = red[1][0];
    #pragma unroll
    for (int i = 0; i < 4; i++) {
        int c = threadIdx.x + i * 256;
        out[(size_t)t * DMODEL + c] = gamma[c] * (y[i] - mu) * inv + beta[c];
    }
}

// ---------------------------------------------------------------------------
extern "C" void kernel_launch(void* const* d_in, const int* in_sizes, int n_in,
                              void* d_out, int out_size, void* d_ws, size_t ws_size,
                              hipStream_t stream)
{
    const float* x     = (const float*)d_in[0];
    const float* Wg    = (const float*)d_in[1];
    const float* bg    = (const float*)d_in[2];
    const float* W1    = (const float*)d_in[3];
    const float* b1    = (const float*)d_in[4];
    const float* W2    = (const float*)d_in[5];
    const float* b2    = (const float*)d_in[6];
    const float* gamma = (const float*)d_in[7];
    const float* beta  = (const float*)d_in[8];
    float* out = (float*)d_out;

    char* ws = (char*)d_ws;
    size_t o = 0;
    auto alloc = [&](size_t bytes) {
        size_t r = o;
        o = (o + bytes + 255) & ~(size_t)255;
        return r;
    };
    size_t o_counts  = alloc(NEXP * 4);
    size_t o_cursor  = alloc(NEXP * 4);
    size_t o_offs    = alloc((NEXP + 1) * 4);
    size_t o_topidx  = alloc((size_t)T_TOKENS * 2 * 4);
    size_t o_topw    = alloc((size_t)T_TOKENS * 2 * 4);
    size_t o_slottok = alloc((size_t)MAXSLOTS * 4);
    size_t o_slotof  = alloc((size_t)T_TOKENS * 2 * 4);
    size_t o_w1t     = alloc((size_t)NEXP * DMODEL * FFN * 2);
    size_t o_w2t     = alloc((size_t)NEXP * DMODEL * FFN * 2);
    size_t o_xg      = alloc((size_t)MAXSLOTS * DMODEL * 2);
    size_t o_h       = alloc((size_t)MAXSLOTS * FFN * 2);
    size_t o_obuf    = alloc((size_t)MAXSLOTS * DMODEL * 4);
    (void)ws_size; (void)in_sizes; (void)n_in; (void)out_size;

    int*      counts     = (int*)(ws + o_counts);
    int*      cursor     = (int*)(ws + o_cursor);
    int*      offs       = (int*)(ws + o_offs);
    int*      top_idx    = (int*)(ws + o_topidx);
    float*    top_w      = (float*)(ws + o_topw);
    int*      slot_token = (int*)(ws + o_slottok);
    int*      slot_of    = (int*)(ws + o_slotof);
    ushort_t* W1T        = (ushort_t*)(ws + o_w1t);
    ushort_t* W2T        = (ushort_t*)(ws + o_w2t);
    ushort_t* Xg         = (ushort_t*)(ws + o_xg);
    ushort_t* H          = (ushort_t*)(ws + o_h);
    float*    Obuf       = (float*)(ws + o_obuf);

    init_kernel<<<(MAXSLOTS + 255) / 256, 256, 0, stream>>>(counts, cursor, slot_token);
    gate_kernel<<<T_TOKENS, 64, 0, stream>>>(x, Wg, bg, top_idx, top_w, counts);
    offsets_kernel<<<1, 64, 0, stream>>>(counts, offs);
    scatter_kernel<<<T_TOKENS / 256, 256, 0, stream>>>(top_idx, offs, cursor, slot_token, slot_of);
    gather_kernel<<<MAXSLOTS, 256, 0, stream>>>(x, slot_token, Xg);
    transpose_kernel<<<dim3(FFN / 64, DMODEL / 64, NEXP), 256, 0, stream>>>(W1, W1T, DMODEL, FFN);
    transpose_kernel<<<dim3(DMODEL / 64, FFN / 64, NEXP), 256, 0, stream>>>(W2, W2T, FFN, DMODEL);
    expert_gemm<DMODEL, FFN, true, ushort_t>
        <<<dim3(FFN / 128, 32, NEXP), 256, 0, stream>>>(Xg, W1T, b1, H, offs);
    expert_gemm<FFN, DMODEL, false, float>
        <<<dim3(DMODEL / 128, 32, NEXP), 256, 0, stream>>>(H, W2T, b2, Obuf, offs);
    ln_kernel<<<T_TOKENS, 256, 0, stream>>>(x, Obuf, slot_of, top_w, gamma, beta, out);
}

// Round 2
// 337.458 us; speedup vs baseline: 1.3566x; 1.3566x over previous
//
#include <hip/hip_runtime.h>

// ---------------------------------------------------------------------------
// MoE block: x[2,2048,1024] fp32, 8 experts, top-2 routing, f=2048, LN output.
// v2: removed all global atomics (gate/scatter were serializing ~8192 RMWs on
// one cacheline = 100+ us each). LDS histograms + prefix scan instead.
// ---------------------------------------------------------------------------

typedef unsigned short ushort_t;
typedef short short8 __attribute__((ext_vector_type(8)));
typedef float f32x4 __attribute__((ext_vector_type(4)));

#define T_TOKENS 4096
#define DMODEL 1024
#define FFN 2048
#define NEXP 8
#define MAXSLOTS 9216
#define GATE_BLOCKS 256
#define TOK_PER_BLK 16

__device__ __forceinline__ ushort_t f2bf(float f) {
    unsigned u = __float_as_uint(f);
    return (ushort_t)((u + 0x7fffu + ((u >> 16) & 1u)) >> 16);
}
__device__ __forceinline__ float bflo(unsigned packed) {
    return __uint_as_float(packed << 16);
}
__device__ __forceinline__ float bfhi(unsigned packed) {
    return __uint_as_float(packed & 0xffff0000u);
}

__device__ __forceinline__ void gload_lds16(const void* g, void* l) {
    __builtin_amdgcn_global_load_lds(
        (const __attribute__((address_space(1))) unsigned int*)g,
        (__attribute__((address_space(3))) unsigned int*)l,
        16, 0, 0);
}

// ---------------------------------------------------------------------------
// 1) init: slot_token = -1 (pad slots must read as invalid for gather)
__global__ void init_kernel(int* slot_token) {
    int i = blockIdx.x * 256 + threadIdx.x;
    if (i < MAXSLOTS) slot_token[i] = -1;
}

// ---------------------------------------------------------------------------
// 2) gating: fp32 logits (Wg register-cached), top-2, softmax weights.
//    Per-block LDS histogram; per-(block,expert) position packed into top_idx.
__global__ __launch_bounds__(256) void gate_kernel(
    const float* __restrict__ x, const float* __restrict__ Wg,
    const float* __restrict__ bg,
    int* __restrict__ top_idx, float* __restrict__ top_w,
    int* __restrict__ blk_hist)
{
    __shared__ int hist[NEXP];
    const int tid = threadIdx.x, lane = tid & 63, w = tid >> 6;
    if (tid < NEXP) hist[tid] = 0;
    __syncthreads();

    // register-cache this lane's Wg slice: d = i*64 + lane, all 8 experts
    float wreg[16][8];
    #pragma unroll
    for (int i = 0; i < 16; i++) {
        const float4* wp = (const float4*)&Wg[(i * 64 + lane) * 8];
        float4 a = wp[0], b = wp[1];
        wreg[i][0] = a.x; wreg[i][1] = a.y; wreg[i][2] = a.z; wreg[i][3] = a.w;
        wreg[i][4] = b.x; wreg[i][5] = b.y; wreg[i][6] = b.z; wreg[i][7] = b.w;
    }
    float bgv[8];
    #pragma unroll
    for (int e = 0; e < 8; e++) bgv[e] = bg[e];

    const int t0 = blockIdx.x * TOK_PER_BLK + w * 4;
    #pragma unroll 1
    for (int it = 0; it < 4; it++) {
        int t = t0 + it;
        const float* xr = x + (size_t)t * DMODEL;
        float acc[8] = {0.f,0.f,0.f,0.f,0.f,0.f,0.f,0.f};
        #pragma unroll
        for (int i = 0; i < 16; i++) {
            float xv = xr[i * 64 + lane];
            #pragma unroll
            for (int e = 0; e < 8; e++) acc[e] += xv * wreg[i][e];
        }
        #pragma unroll
        for (int off = 32; off > 0; off >>= 1) {
            #pragma unroll
            for (int e = 0; e < 8; e++) acc[e] += __shfl_down(acc[e], off);
        }
        if (lane == 0) {
            float l[8];
            #pragma unroll
            for (int e = 0; e < 8; e++) l[e] = acc[e] + bgv[e];
            int i0 = 0; float v0 = l[0];
            #pragma unroll
            for (int e = 1; e < 8; e++) if (l[e] > v0) { v0 = l[e]; i0 = e; }
            int i1 = -1; float v1 = -1e30f;
            #pragma unroll
            for (int e = 0; e < 8; e++) if (e != i0 && l[e] > v1) { v1 = l[e]; i1 = e; }
            float eg = expf(v1 - v0);
            float den = 1.f + eg;
            int p0 = atomicAdd(&hist[i0], 1);
            int p1 = atomicAdd(&hist[i1], 1);
            top_idx[2 * t]     = i0 | (p0 << 4);
            top_idx[2 * t + 1] = i1 | (p1 << 4);
            top_w[2 * t]     = 1.f / den;
            top_w[2 * t + 1] = eg / den;
        }
    }
    __syncthreads();
    if (tid < NEXP) blk_hist[blockIdx.x * NEXP + tid] = hist[tid];
}

// ---------------------------------------------------------------------------
// 3) scan: per-expert exclusive prefix over block histograms + padded offsets.
//    One block, 8 waves; wave e scans expert e.
__global__ __launch_bounds__(512) void scan_kernel(
    const int* __restrict__ blk_hist, int* __restrict__ blk_base,
    int* __restrict__ offs)
{
    __shared__ int cnt[NEXP];
    const int tid = threadIdx.x, lane = tid & 63, e = tid >> 6;
    int carry = 0;
    #pragma unroll
    for (int r = 0; r < GATE_BLOCKS / 64; r++) {
        int b = r * 64 + lane;
        int orig = blk_hist[b * NEXP + e];
        int v = orig;
        #pragma unroll
        for (int off = 1; off < 64; off <<= 1) {
            int u = __shfl_up(v, off);
            if (lane >= off) v += u;
        }
        blk_base[b * NEXP + e] = carry + v - orig;
        carry += __shfl(v, 63);
    }
    if (lane == 0) cnt[e] = carry;
    __syncthreads();
    if (tid == 0) {
        int cum = 0;
        for (int ee = 0; ee < NEXP; ee++) {
            offs[ee] = cum;
            cum += (cnt[ee] + 127) & ~127;
        }
        offs[NEXP] = cum;
    }
}

// ---------------------------------------------------------------------------
// 4) scatter: pure function, no atomics
__global__ void scatter_kernel(const int* __restrict__ top_idx,
                               const int* __restrict__ offs,
                               const int* __restrict__ blk_base,
                               int* __restrict__ slot_token,
                               int* __restrict__ slot_of)
{
    int t = blockIdx.x * 256 + threadIdx.x;
    if (t >= T_TOKENS) return;
    int gb = t / TOK_PER_BLK;
    #pragma unroll
    for (int k = 0; k < 2; k++) {
        int v = top_idx[2 * t + k];
        int e = v & 15;
        int pos = v >> 4;
        int slot = offs[e] + blk_base[gb * NEXP + e] + pos;
        slot_token[slot] = t;
        slot_of[2 * t + k] = slot;
    }
}

// ---------------------------------------------------------------------------
// 5) gather x rows into bf16 A-matrix (16B stores)
__global__ __launch_bounds__(256) void gather_kernel(
    const float* __restrict__ x, const int* __restrict__ slot_token,
    ushort_t* __restrict__ Xg)
{
    int row = blockIdx.x * 2 + (threadIdx.x >> 7);
    int c = threadIdx.x & 127;
    int tok = slot_token[row];
    uint4* dst = (uint4*)(Xg + (size_t)row * DMODEL) + c;
    if (tok < 0) {
        *dst = make_uint4(0, 0, 0, 0);
        return;
    }
    const float4* sx = (const float4*)(x + (size_t)tok * DMODEL) + c * 2;
    float4 a = sx[0], b = sx[1];
    uint4 o;
    o.x = f2bf(a.x) | ((unsigned)f2bf(a.y) << 16);
    o.y = f2bf(a.z) | ((unsigned)f2bf(a.w) << 16);
    o.z = f2bf(b.x) | ((unsigned)f2bf(b.y) << 16);
    o.w = f2bf(b.z) | ((unsigned)f2bf(b.w) << 16);
    *dst = o;
}

// ---------------------------------------------------------------------------
// 6) transpose+convert weights: src [E][R][C] f32 -> dst [E][C][R] bf16
//    float4 loads, 8B LDS stores, 8B global stores.
__global__ __launch_bounds__(256) void transpose_kernel(
    const float* __restrict__ src, ushort_t* __restrict__ dst, int R, int C)
{
    __shared__ ushort_t tile[64][68];
    const float* s = src + (size_t)blockIdx.z * R * C;
    ushort_t* d = dst + (size_t)blockIdx.z * R * C;
    int c0 = blockIdx.x * 64, r0 = blockIdx.y * 64;
    int fc = threadIdx.x & 15, rp = threadIdx.x >> 4;
    #pragma unroll
    for (int p = 0; p < 4; p++) {
        int r = p * 16 + rp;
        float4 v = *(const float4*)&s[(size_t)(r0 + r) * C + c0 + fc * 4];
        uint2 pk;
        pk.x = f2bf(v.x) | ((unsigned)f2bf(v.y) << 16);
        pk.y = f2bf(v.z) | ((unsigned)f2bf(v.w) << 16);
        *(uint2*)&tile[r][fc * 4] = pk;
    }
    __syncthreads();
    #pragma unroll
    for (int p = 0; p < 4; p++) {
        int c = p * 16 + rp;
        int rb = fc * 4;
        uint2 pk;
        pk.x = tile[rb + 0][c] | ((unsigned)tile[rb + 1][c] << 16);
        pk.y = tile[rb + 2][c] | ((unsigned)tile[rb + 3][c] << 16);
        *(uint2*)&d[(size_t)(c0 + c) * R + r0 + rb] = pk;
    }
}

// ---------------------------------------------------------------------------
// 7) grouped expert GEMM (m97 structure): C = A[M,K] * Bt[N,K]^T + bias
template <int K, int N, bool RELU, typename OutT>
__global__ __launch_bounds__(256) void expert_gemm(
    const ushort_t* __restrict__ A,
    const ushort_t* __restrict__ Bt,
    const float* __restrict__ bias,
    OutT* __restrict__ Cout,
    const int* __restrict__ offs)
{
    const int e  = blockIdx.z;
    const int mt = blockIdx.y;
    const int nt = blockIdx.x;
    const int off_e = offs[e];
    const int Mpad  = offs[e + 1] - off_e;
    if (mt * 128 >= Mpad) return;

    __shared__ __align__(16) ushort_t As[128 * 32];
    __shared__ __align__(16) ushort_t Bs[128 * 32];

    const int tid  = threadIdx.x;
    const int lane = tid & 63;
    const int w    = tid >> 6;
    const int quad = lane >> 4;
    const int r16  = lane & 15;
    const int lrow = lane >> 2;
    const int lk   = (lane & 3) * 8;

    const size_t arow0 = (size_t)(off_e + mt * 128);
    const ushort_t* aS0 = A + (arow0 + (size_t)(2 * w + 0) * 16 + lrow) * K + lk;
    const ushort_t* aS1 = A + (arow0 + (size_t)(2 * w + 1) * 16 + lrow) * K + lk;
    const ushort_t* Bte = Bt + (size_t)e * N * K;
    const ushort_t* bS0 = Bte + ((size_t)(nt * 128 + (2 * w + 0) * 16 + lrow)) * K + lk;
    const ushort_t* bS1 = Bte + ((size_t)(nt * 128 + (2 * w + 1) * 16 + lrow)) * K + lk;
    ushort_t* aD0 = &As[(2 * w + 0) * 512];
    ushort_t* aD1 = &As[(2 * w + 1) * 512];
    ushort_t* bD0 = &Bs[(2 * w + 0) * 512];
    ushort_t* bD1 = &Bs[(2 * w + 1) * 512];

    const int wm = (w >> 1) * 64;
    const int wn = (w & 1) * 64;

    f32x4 acc[4][4];
    #pragma unroll
    for (int i = 0; i < 4; i++)
        #pragma unroll
        for (int j = 0; j < 4; j++)
            acc[i][j] = (f32x4){0.f, 0.f, 0.f, 0.f};

    for (int k0 = 0; k0 < K; k0 += 32) {
        gload_lds16(aS0 + k0, aD0);
        gload_lds16(aS1 + k0, aD1);
        gload_lds16(bS0 + k0, bD0);
        gload_lds16(bS1 + k0, bD1);
        __syncthreads();
        short8 af[4], bfr[4];
        #pragma unroll
        for (int i = 0; i < 4; i++)
            af[i] = *(const short8*)&As[(wm + i * 16 + r16) * 32 + quad * 8];
        #pragma unroll
        for (int j = 0; j < 4; j++)
            bfr[j] = *(const short8*)&Bs[(wn + j * 16 + r16) * 32 + quad * 8];
        #pragma unroll
        for (int i = 0; i < 4; i++)
            #pragma unroll
            for (int j = 0; j < 4; j++)
                acc[i][j] = __builtin_amdgcn_mfma_f32_16x16x32_bf16(
                    af[i], bfr[j], acc[i][j], 0, 0, 0);
        __syncthreads();
    }

    const float* be = bias + (size_t)e * N;
    #pragma unroll
    for (int i = 0; i < 4; i++) {
        #pragma unroll
        for (int j = 0; j < 4; j++) {
            int n = nt * 128 + wn + j * 16 + r16;
            float bv = be[n];
            #pragma unroll
            for (int r = 0; r < 4; r++) {
                int m = mt * 128 + wm + i * 16 + quad * 4 + r;
                float v = acc[i][j][r] + bv;
                if (RELU) v = v > 0.f ? v : 0.f;
                size_t idx = (size_t)(off_e + m) * N + n;
                if constexpr (sizeof(OutT) == 2)
                    ((ushort_t*)Cout)[idx] = f2bf(v);
                else
                    ((float*)Cout)[idx] = v;
            }
        }
    }
}

// ---------------------------------------------------------------------------
// 8) fused mix + residual + LayerNorm (bf16 expert outputs, vectorized)
__global__ __launch_bounds__(256) void ln_kernel(
    const float* __restrict__ x, const ushort_t* __restrict__ O,
    const int* __restrict__ slot_of, const float* __restrict__ top_w,
    const float* __restrict__ gamma, const float* __restrict__ beta,
    float* __restrict__ out)
{
    int t = blockIdx.x, tid = threadIdx.x;
    int s0 = slot_of[2 * t], s1 = slot_of[2 * t + 1];
    float w0 = top_w[2 * t], w1 = top_w[2 * t + 1];
    float4 xv = ((const float4*)(x + (size_t)t * DMODEL))[tid];
    uint2 a = ((const uint2*)(O + (size_t)s0 * DMODEL))[tid];
    uint2 b = ((const uint2*)(O + (size_t)s1 * DMODEL))[tid];

    float y[4];
    y[0] = xv.x + w0 * bflo(a.x) + w1 * bflo(b.x);
    y[1] = xv.y + w0 * bfhi(a.x) + w1 * bfhi(b.x);
    y[2] = xv.z + w0 * bflo(a.y) + w1 * bflo(b.y);
    y[3] = xv.w + w0 * bfhi(a.y) + w1 * bfhi(b.y);

    float s = y[0] + y[1] + y[2] + y[3];
    float sq = y[0]*y[0] + y[1]*y[1] + y[2]*y[2] + y[3]*y[3];
    __shared__ float red[2][4];
    #pragma unroll
    for (int off = 32; off > 0; off >>= 1) {
        s += __shfl_down(s, off);
        sq += __shfl_down(sq, off);
    }
    int lane = tid & 63, wv = tid >> 6;
    if (lane == 0) { red[0][wv] = s; red[1][wv] = sq; }
    __syncthreads();
    if (tid == 0) {
        float S = red[0][0] + red[0][1] + red[0][2] + red[0][3];
        float SQ = red[1][0] + red[1][1] + red[1][2] + red[1][3];
        float mu = S * (1.f / DMODEL);
        float var = SQ * (1.f / DMODEL) - mu * mu;
        red[0][0] = mu;
        red[1][0] = rsqrtf(var + 1e-5f);
    }
    __syncthreads();
    float mu = red[0][0], inv = red[1][0];
    float4 gv = ((const float4*)gamma)[tid];
    float4 bv = ((const float4*)beta)[tid];
    float4 ov;
    ov.x = gv.x * (y[0] - mu) * inv + bv.x;
    ov.y = gv.y * (y[1] - mu) * inv + bv.y;
    ov.z = gv.z * (y[2] - mu) * inv + bv.z;
    ov.w = gv.w * (y[3] - mu) * inv + bv.w;
    ((float4*)(out + (size_t)t * DMODEL))[tid] = ov;
}

// ---------------------------------------------------------------------------
extern "C" void kernel_launch(void* const* d_in, const int* in_sizes, int n_in,
                              void* d_out, int out_size, void* d_ws, size_t ws_size,
                              hipStream_t stream)
{
    const float* x     = (const float*)d_in[0];
    const float* Wg    = (const float*)d_in[1];
    const float* bg    = (const float*)d_in[2];
    const float* W1    = (const float*)d_in[3];
    const float* b1    = (const float*)d_in[4];
    const float* W2    = (const float*)d_in[5];
    const float* b2    = (const float*)d_in[6];
    const float* gamma = (const float*)d_in[7];
    const float* beta  = (const float*)d_in[8];
    float* out = (float*)d_out;

    char* ws = (char*)d_ws;
    size_t o = 0;
    auto alloc = [&](size_t bytes) {
        size_t r = o;
        o = (o + bytes + 255) & ~(size_t)255;
        return r;
    };
    size_t o_offs    = alloc((NEXP + 1) * 4);
    size_t o_topidx  = alloc((size_t)T_TOKENS * 2 * 4);
    size_t o_topw    = alloc((size_t)T_TOKENS * 2 * 4);
    size_t o_slottok = alloc((size_t)MAXSLOTS * 4);
    size_t o_slotof  = alloc((size_t)T_TOKENS * 2 * 4);
    size_t o_bhist   = alloc((size_t)GATE_BLOCKS * NEXP * 4);
    size_t o_bbase   = alloc((size_t)GATE_BLOCKS * NEXP * 4);
    size_t o_w1t     = alloc((size_t)NEXP * DMODEL * FFN * 2);
    size_t o_w2t     = alloc((size_t)NEXP * DMODEL * FFN * 2);
    size_t o_xg      = alloc((size_t)MAXSLOTS * DMODEL * 2);
    size_t o_h       = alloc((size_t)MAXSLOTS * FFN * 2);
    size_t o_obuf    = alloc((size_t)MAXSLOTS * DMODEL * 2);
    (void)ws_size; (void)in_sizes; (void)n_in; (void)out_size;

    int*      offs       = (int*)(ws + o_offs);
    int*      top_idx    = (int*)(ws + o_topidx);
    float*    top_w      = (float*)(ws + o_topw);
    int*      slot_token = (int*)(ws + o_slottok);
    int*      slot_of    = (int*)(ws + o_slotof);
    int*      blk_hist   = (int*)(ws + o_bhist);
    int*      blk_base   = (int*)(ws + o_bbase);
    ushort_t* W1T        = (ushort_t*)(ws + o_w1t);
    ushort_t* W2T        = (ushort_t*)(ws + o_w2t);
    ushort_t* Xg         = (ushort_t*)(ws + o_xg);
    ushort_t* H          = (ushort_t*)(ws + o_h);
    ushort_t* Obuf       = (ushort_t*)(ws + o_obuf);

    init_kernel<<<MAXSLOTS / 256, 256, 0, stream>>>(slot_token);
    gate_kernel<<<GATE_BLOCKS, 256, 0, stream>>>(x, Wg, bg, top_idx, top_w, blk_hist);
    scan_kernel<<<1, 512, 0, stream>>>(blk_hist, blk_base, offs);
    scatter_kernel<<<T_TOKENS / 256, 256, 0, stream>>>(top_idx, offs, blk_base, slot_token, slot_of);
    gather_kernel<<<MAXSLOTS / 2, 256, 0, stream>>>(x, slot_token, Xg);
    transpose_kernel<<<dim3(FFN / 64, DMODEL / 64, NEXP), 256, 0, stream>>>(W1, W1T, DMODEL, FFN);
    transpose_kernel<<<dim3(DMODEL / 64, FFN / 64, NEXP), 256, 0, stream>>>(W2, W2T, FFN, DMODEL);
    expert_gemm<DMODEL, FFN, true, ushort_t>
        <<<dim3(FFN / 128, 32, NEXP), 256, 0, stream>>>(Xg, W1T, b1, H, offs);
    expert_gemm<FFN, DMODEL, false, ushort_t>
        <<<dim3(DMODEL / 128, 32, NEXP), 256, 0, stream>>>(H, W2T, b2, Obuf, offs);
    ln_kernel<<<T_TOKENS, 256, 0, stream>>>(x, Obuf, slot_of, top_w, gamma, beta, out);
}

// Round 3
// 316.323 us; speedup vs baseline: 1.4473x; 1.0668x over previous
//
#include <hip/hip_runtime.h>

// ---------------------------------------------------------------------------
// MoE block: x[2,2048,1024] fp32, 8 experts, top-2 routing, f=2048, LN output.
// v3: XCD-pinned expert GEMMs (gridDim.x=8=expert -> flat%8 = XCD = expert,
//     per-XCD L2 holds exactly one expert's 4MB weights), XOR-swizzled LDS
//     staging (kills the 8-way bank conflicts), launches 10 -> 7
//     (init/slot_token dropped; scatter+gather fused; transposes fused).
// ---------------------------------------------------------------------------

typedef unsigned short ushort_t;
typedef short short8 __attribute__((ext_vector_type(8)));
typedef float f32x4 __attribute__((ext_vector_type(4)));

#define T_TOKENS 4096
#define DMODEL 1024
#define FFN 2048
#define NEXP 8
#define MAXSLOTS 9216
#define GATE_BLOCKS 256
#define TOK_PER_BLK 16

__device__ __forceinline__ ushort_t f2bf(float f) {
    unsigned u = __float_as_uint(f);
    return (ushort_t)((u + 0x7fffu + ((u >> 16) & 1u)) >> 16);
}
__device__ __forceinline__ float bflo(unsigned packed) {
    return __uint_as_float(packed << 16);
}
__device__ __forceinline__ float bfhi(unsigned packed) {
    return __uint_as_float(packed & 0xffff0000u);
}

__device__ __forceinline__ void gload_lds16(const void* g, void* l) {
    __builtin_amdgcn_global_load_lds(
        (const __attribute__((address_space(1))) unsigned int*)g,
        (__attribute__((address_space(3))) unsigned int*)l,
        16, 0, 0);
}

// ---------------------------------------------------------------------------
// 1) gating: fp32 logits (Wg register-cached), top-2, softmax weights.
//    Per-block LDS histogram; per-(block,expert) position packed into top_idx.
__global__ __launch_bounds__(256) void gate_kernel(
    const float* __restrict__ x, const float* __restrict__ Wg,
    const float* __restrict__ bg,
    int* __restrict__ top_idx, float* __restrict__ top_w,
    int* __restrict__ blk_hist)
{
    __shared__ int hist[NEXP];
    const int tid = threadIdx.x, lane = tid & 63, w = tid >> 6;
    if (tid < NEXP) hist[tid] = 0;
    __syncthreads();

    float wreg[16][8];
    #pragma unroll
    for (int i = 0; i < 16; i++) {
        const float4* wp = (const float4*)&Wg[(i * 64 + lane) * 8];
        float4 a = wp[0], b = wp[1];
        wreg[i][0] = a.x; wreg[i][1] = a.y; wreg[i][2] = a.z; wreg[i][3] = a.w;
        wreg[i][4] = b.x; wreg[i][5] = b.y; wreg[i][6] = b.z; wreg[i][7] = b.w;
    }
    float bgv[8];
    #pragma unroll
    for (int e = 0; e < 8; e++) bgv[e] = bg[e];

    const int t0 = blockIdx.x * TOK_PER_BLK + w * 4;
    #pragma unroll 1
    for (int it = 0; it < 4; it++) {
        int t = t0 + it;
        const float* xr = x + (size_t)t * DMODEL;
        float acc[8] = {0.f,0.f,0.f,0.f,0.f,0.f,0.f,0.f};
        #pragma unroll
        for (int i = 0; i < 16; i++) {
            float xv = xr[i * 64 + lane];
            #pragma unroll
            for (int e = 0; e < 8; e++) acc[e] += xv * wreg[i][e];
        }
        #pragma unroll
        for (int off = 32; off > 0; off >>= 1) {
            #pragma unroll
            for (int e = 0; e < 8; e++) acc[e] += __shfl_down(acc[e], off);
        }
        if (lane == 0) {
            float l[8];
            #pragma unroll
            for (int e = 0; e < 8; e++) l[e] = acc[e] + bgv[e];
            int i0 = 0; float v0 = l[0];
            #pragma unroll
            for (int e = 1; e < 8; e++) if (l[e] > v0) { v0 = l[e]; i0 = e; }
            int i1 = -1; float v1 = -1e30f;
            #pragma unroll
            for (int e = 0; e < 8; e++) if (e != i0 && l[e] > v1) { v1 = l[e]; i1 = e; }
            float eg = expf(v1 - v0);
            float den = 1.f + eg;
            int p0 = atomicAdd(&hist[i0], 1);
            int p1 = atomicAdd(&hist[i1], 1);
            top_idx[2 * t]     = i0 | (p0 << 4);
            top_idx[2 * t + 1] = i1 | (p1 << 4);
            top_w[2 * t]     = 1.f / den;
            top_w[2 * t + 1] = eg / den;
        }
    }
    __syncthreads();
    if (tid < NEXP) blk_hist[blockIdx.x * NEXP + tid] = hist[tid];
}

// ---------------------------------------------------------------------------
// 2) scan: per-expert exclusive prefix over block histograms + padded offsets.
__global__ __launch_bounds__(512) void scan_kernel(
    const int* __restrict__ blk_hist, int* __restrict__ blk_base,
    int* __restrict__ offs)
{
    __shared__ int cnt[NEXP];
    const int tid = threadIdx.x, lane = tid & 63, e = tid >> 6;
    int carry = 0;
    #pragma unroll
    for (int r = 0; r < GATE_BLOCKS / 64; r++) {
        int b = r * 64 + lane;
        int orig = blk_hist[b * NEXP + e];
        int v = orig;
        #pragma unroll
        for (int off = 1; off < 64; off <<= 1) {
            int u = __shfl_up(v, off);
            if (lane >= off) v += u;
        }
        blk_base[b * NEXP + e] = carry + v - orig;
        carry += __shfl(v, 63);
    }
    if (lane == 0) cnt[e] = carry;
    __syncthreads();
    if (tid == 0) {
        int cum = 0;
        for (int ee = 0; ee < NEXP; ee++) {
            offs[ee] = cum;
            cum += (cnt[ee] + 127) & ~127;
        }
        offs[NEXP] = cum;
    }
}

// ---------------------------------------------------------------------------
// 3) fused scatter + gather: one block per token; computes both slots, writes
//    slot_of, and stores the bf16 row to both expert buckets.
//    (Pad slots keep 0xAA poison - their GEMM outputs are never read.)
__global__ __launch_bounds__(256) void scatter_gather_kernel(
    const float* __restrict__ x, const int* __restrict__ top_idx,
    const int* __restrict__ offs, const int* __restrict__ blk_base,
    int* __restrict__ slot_of, ushort_t* __restrict__ Xg)
{
    const int t = blockIdx.x, tid = threadIdx.x;
    __shared__ int slots[2];
    if (tid < 2) {
        int v = top_idx[2 * t + tid];
        int e = v & 15, pos = v >> 4;
        int gb = t / TOK_PER_BLK;
        int slot = offs[e] + blk_base[gb * NEXP + e] + pos;
        slot_of[2 * t + tid] = slot;
        slots[tid] = slot;
    }
    __syncthreads();
    float4 xv = ((const float4*)(x + (size_t)t * DMODEL))[tid];
    uint2 pk;
    pk.x = f2bf(xv.x) | ((unsigned)f2bf(xv.y) << 16);
    pk.y = f2bf(xv.z) | ((unsigned)f2bf(xv.w) << 16);
    ((uint2*)(Xg + (size_t)slots[0] * DMODEL))[tid] = pk;
    ((uint2*)(Xg + (size_t)slots[1] * DMODEL))[tid] = pk;
}

// ---------------------------------------------------------------------------
// 4) fused transpose+convert for both weights: [E][R][C] f32 -> [E][C][R] bf16
__global__ __launch_bounds__(256) void transpose_kernel(
    const float* __restrict__ W1, const float* __restrict__ W2,
    ushort_t* __restrict__ W1T, ushort_t* __restrict__ W2T)
{
    __shared__ ushort_t tile[64][68];
    int b = blockIdx.x;
    const float* s; ushort_t* d; int R, C, rt, ct;
    if (b < 4096) {                 // W1: R=1024, C=2048 -> 16 x 32 tiles
        int e = b >> 9, t = b & 511;
        rt = t >> 5; ct = t & 31;
        s = W1 + (size_t)e * DMODEL * FFN;
        d = W1T + (size_t)e * DMODEL * FFN;
        R = DMODEL; C = FFN;
    } else {                        // W2: R=2048, C=1024 -> 32 x 16 tiles
        b -= 4096;
        int e = b >> 9, t = b & 511;
        rt = t >> 4; ct = t & 15;
        s = W2 + (size_t)e * DMODEL * FFN;
        d = W2T + (size_t)e * DMODEL * FFN;
        R = FFN; C = DMODEL;
    }
    int r0 = rt * 64, c0 = ct * 64;
    int fc = threadIdx.x & 15, rp = threadIdx.x >> 4;
    #pragma unroll
    for (int p = 0; p < 4; p++) {
        int r = p * 16 + rp;
        float4 v = *(const float4*)&s[(size_t)(r0 + r) * C + c0 + fc * 4];
        uint2 pk;
        pk.x = f2bf(v.x) | ((unsigned)f2bf(v.y) << 16);
        pk.y = f2bf(v.z) | ((unsigned)f2bf(v.w) << 16);
        *(uint2*)&tile[r][fc * 4] = pk;
    }
    __syncthreads();
    #pragma unroll
    for (int p = 0; p < 4; p++) {
        int c = p * 16 + rp;
        int rb = fc * 4;
        uint2 pk;
        pk.x = tile[rb + 0][c] | ((unsigned)tile[rb + 1][c] << 16);
        pk.y = tile[rb + 2][c] | ((unsigned)tile[rb + 3][c] << 16);
        *(uint2*)&d[(size_t)(c0 + c) * R + r0 + rb] = pk;
    }
}

// ---------------------------------------------------------------------------
// 5) grouped expert GEMM: C = A[M,K] * Bt[N,K]^T + bias, bf16 out.
//    gridDim.x = 8 = expert -> XCD pinning (flat%8 == expert).
//    XOR-swizzled LDS chunks: cell(row, c16) holds k-chunk c16 ^ ((row>>1)&3).
template <int K, int N, bool RELU>
__global__ __launch_bounds__(256) void expert_gemm(
    const ushort_t* __restrict__ A,
    const ushort_t* __restrict__ Bt,
    const float* __restrict__ bias,
    ushort_t* __restrict__ Cout,
    const int* __restrict__ offs)
{
    const int e  = blockIdx.x;
    const int nt = blockIdx.y;
    const int mt = blockIdx.z;
    const int off_e = offs[e];
    const int Mpad  = offs[e + 1] - off_e;
    if (mt * 128 >= Mpad) return;

    __shared__ __align__(16) ushort_t As[128 * 32];
    __shared__ __align__(16) ushort_t Bs[128 * 32];

    const int tid  = threadIdx.x;
    const int lane = tid & 63;
    const int w    = tid >> 6;
    const int quad = lane >> 4;
    const int r16  = lane & 15;
    const int lrow = lane >> 2;                          // staging row 0..15
    const int lk   = (((lane & 3) ^ ((lane >> 3) & 3))) * 8;  // swizzled src k

    const size_t arow0 = (size_t)(off_e + mt * 128);
    const ushort_t* aS0 = A + (arow0 + (size_t)(2 * w + 0) * 16 + lrow) * K + lk;
    const ushort_t* aS1 = A + (arow0 + (size_t)(2 * w + 1) * 16 + lrow) * K + lk;
    const ushort_t* Bte = Bt + (size_t)e * N * K;
    const ushort_t* bS0 = Bte + ((size_t)(nt * 128 + (2 * w + 0) * 16 + lrow)) * K + lk;
    const ushort_t* bS1 = Bte + ((size_t)(nt * 128 + (2 * w + 1) * 16 + lrow)) * K + lk;
    ushort_t* aD0 = &As[(2 * w + 0) * 512];
    ushort_t* aD1 = &As[(2 * w + 1) * 512];
    ushort_t* bD0 = &Bs[(2 * w + 0) * 512];
    ushort_t* bD1 = &Bs[(2 * w + 1) * 512];

    const int wm = (w >> 1) * 64;
    const int wn = (w & 1) * 64;
    const int sw = ((r16 >> 1) & 3) ^ quad;   // swizzled read chunk

    f32x4 acc[4][4];
    #pragma unroll
    for (int i = 0; i < 4; i++)
        #pragma unroll
        for (int j = 0; j < 4; j++)
            acc[i][j] = (f32x4){0.f, 0.f, 0.f, 0.f};

    for (int k0 = 0; k0 < K; k0 += 32) {
        gload_lds16(aS0 + k0, aD0);
        gload_lds16(aS1 + k0, aD1);
        gload_lds16(bS0 + k0, bD0);
        gload_lds16(bS1 + k0, bD1);
        __syncthreads();
        short8 af[4], bfr[4];
        #pragma unroll
        for (int i = 0; i < 4; i++)
            af[i] = *(const short8*)&As[(wm + i * 16 + r16) * 32 + sw * 8];
        #pragma unroll
        for (int j = 0; j < 4; j++)
            bfr[j] = *(const short8*)&Bs[(wn + j * 16 + r16) * 32 + sw * 8];
        #pragma unroll
        for (int i = 0; i < 4; i++)
            #pragma unroll
            for (int j = 0; j < 4; j++)
                acc[i][j] = __builtin_amdgcn_mfma_f32_16x16x32_bf16(
                    af[i], bfr[j], acc[i][j], 0, 0, 0);
        __syncthreads();
    }

    const float* be = bias + (size_t)e * N;
    #pragma unroll
    for (int i = 0; i < 4; i++) {
        #pragma unroll
        for (int j = 0; j < 4; j++) {
            int n = nt * 128 + wn + j * 16 + r16;
            float bv = be[n];
            #pragma unroll
            for (int r = 0; r < 4; r++) {
                int m = mt * 128 + wm + i * 16 + quad * 4 + r;
                float v = acc[i][j][r] + bv;
                if (RELU) v = v > 0.f ? v : 0.f;
                Cout[(size_t)(off_e + m) * N + n] = f2bf(v);
            }
        }
    }
}

// ---------------------------------------------------------------------------
// 6) fused mix + residual + LayerNorm (bf16 expert outputs, vectorized)
__global__ __launch_bounds__(256) void ln_kernel(
    const float* __restrict__ x, const ushort_t* __restrict__ O,
    const int* __restrict__ slot_of, const float* __restrict__ top_w,
    const float* __restrict__ gamma, const float* __restrict__ beta,
    float* __restrict__ out)
{
    int t = blockIdx.x, tid = threadIdx.x;
    int s0 = slot_of[2 * t], s1 = slot_of[2 * t + 1];
    float w0 = top_w[2 * t], w1 = top_w[2 * t + 1];
    float4 xv = ((const float4*)(x + (size_t)t * DMODEL))[tid];
    uint2 a = ((const uint2*)(O + (size_t)s0 * DMODEL))[tid];
    uint2 b = ((const uint2*)(O + (size_t)s1 * DMODEL))[tid];

    float y[4];
    y[0] = xv.x + w0 * bflo(a.x) + w1 * bflo(b.x);
    y[1] = xv.y + w0 * bfhi(a.x) + w1 * bfhi(b.x);
    y[2] = xv.z + w0 * bflo(a.y) + w1 * bflo(b.y);
    y[3] = xv.w + w0 * bfhi(a.y) + w1 * bfhi(b.y);

    float s = y[0] + y[1] + y[2] + y[3];
    float sq = y[0]*y[0] + y[1]*y[1] + y[2]*y[2] + y[3]*y[3];
    __shared__ float red[2][4];
    #pragma unroll
    for (int off = 32; off > 0; off >>= 1) {
        s += __shfl_down(s, off);
        sq += __shfl_down(sq, off);
    }
    int lane = tid & 63, wv = tid >> 6;
    if (lane == 0) { red[0][wv] = s; red[1][wv] = sq; }
    __syncthreads();
    if (tid == 0) {
        float S = red[0][0] + red[0][1] + red[0][2] + red[0][3];
        float SQ = red[1][0] + red[1][1] + red[1][2] + red[1][3];
        float mu = S * (1.f / DMODEL);
        float var = SQ * (1.f / DMODEL) - mu * mu;
        red[0][0] = mu;
        red[1][0] = rsqrtf(var + 1e-5f);
    }
    __syncthreads();
    float mu = red[0][0], inv = red[1][0];
    float4 gv = ((const float4*)gamma)[tid];
    float4 bv = ((const float4*)beta)[tid];
    float4 ov;
    ov.x = gv.x * (y[0] - mu) * inv + bv.x;
    ov.y = gv.y * (y[1] - mu) * inv + bv.y;
    ov.z = gv.z * (y[2] - mu) * inv + bv.z;
    ov.w = gv.w * (y[3] - mu) * inv + bv.w;
    ((float4*)(out + (size_t)t * DMODEL))[tid] = ov;
}

// ---------------------------------------------------------------------------
extern "C" void kernel_launch(void* const* d_in, const int* in_sizes, int n_in,
                              void* d_out, int out_size, void* d_ws, size_t ws_size,
                              hipStream_t stream)
{
    const float* x     = (const float*)d_in[0];
    const float* Wg    = (const float*)d_in[1];
    const float* bg    = (const float*)d_in[2];
    const float* W1    = (const float*)d_in[3];
    const float* b1    = (const float*)d_in[4];
    const float* W2    = (const float*)d_in[5];
    const float* b2    = (const float*)d_in[6];
    const float* gamma = (const float*)d_in[7];
    const float* beta  = (const float*)d_in[8];
    float* out = (float*)d_out;

    char* ws = (char*)d_ws;
    size_t o = 0;
    auto alloc = [&](size_t bytes) {
        size_t r = o;
        o = (o + bytes + 255) & ~(size_t)255;
        return r;
    };
    size_t o_offs    = alloc((NEXP + 1) * 4);
    size_t o_topidx  = alloc((size_t)T_TOKENS * 2 * 4);
    size_t o_topw    = alloc((size_t)T_TOKENS * 2 * 4);
    size_t o_slotof  = alloc((size_t)T_TOKENS * 2 * 4);
    size_t o_bhist   = alloc((size_t)GATE_BLOCKS * NEXP * 4);
    size_t o_bbase   = alloc((size_t)GATE_BLOCKS * NEXP * 4);
    size_t o_w1t     = alloc((size_t)NEXP * DMODEL * FFN * 2);
    size_t o_w2t     = alloc((size_t)NEXP * DMODEL * FFN * 2);
    size_t o_xg      = alloc((size_t)MAXSLOTS * DMODEL * 2);
    size_t o_h       = alloc((size_t)MAXSLOTS * FFN * 2);
    size_t o_obuf    = alloc((size_t)MAXSLOTS * DMODEL * 2);
    (void)ws_size; (void)in_sizes; (void)n_in; (void)out_size;

    int*      offs     = (int*)(ws + o_offs);
    int*      top_idx  = (int*)(ws + o_topidx);
    float*    top_w    = (float*)(ws + o_topw);
    int*      slot_of  = (int*)(ws + o_slotof);
    int*      blk_hist = (int*)(ws + o_bhist);
    int*      blk_base = (int*)(ws + o_bbase);
    ushort_t* W1T      = (ushort_t*)(ws + o_w1t);
    ushort_t* W2T      = (ushort_t*)(ws + o_w2t);
    ushort_t* Xg       = (ushort_t*)(ws + o_xg);
    ushort_t* H        = (ushort_t*)(ws + o_h);
    ushort_t* Obuf     = (ushort_t*)(ws + o_obuf);

    gate_kernel<<<GATE_BLOCKS, 256, 0, stream>>>(x, Wg, bg, top_idx, top_w, blk_hist);
    transpose_kernel<<<8192, 256, 0, stream>>>(W1, W2, W1T, W2T);
    scan_kernel<<<1, 512, 0, stream>>>(blk_hist, blk_base, offs);
    scatter_gather_kernel<<<T_TOKENS, 256, 0, stream>>>(x, top_idx, offs, blk_base, slot_of, Xg);
    expert_gemm<DMODEL, FFN, true>
        <<<dim3(NEXP, FFN / 128, 32), 256, 0, stream>>>(Xg, W1T, b1, H, offs);
    expert_gemm<FFN, DMODEL, false>
        <<<dim3(NEXP, DMODEL / 128, 32), 256, 0, stream>>>(H, W2T, b2, Obuf, offs);
    ln_kernel<<<T_TOKENS, 256, 0, stream>>>(x, Obuf, slot_of, top_w, gamma, beta, out);
}